// Round 4
// baseline (170.037 us; speedup 1.0000x reference)
//
#include <hip/hip_runtime.h>
#include <hip/hip_bf16.h>
#include <math.h>

#define C_CH 256

// ---------------------------------------------------------------------------
// Transpose all 4 FPN levels from fp32 (C,H,W) to bf16 (H*W, C) in d_ws.
// 64-spatial x 64-channel tiles, 256 threads, 16.6 KB LDS.
// At the 223 MB (178 rd + 45 wr) / 6.3 TB/s BW roofline (~35 us).
// ---------------------------------------------------------------------------
__global__ __launch_bounds__(256) void transpose_all(
    const float* __restrict__ f0, const float* __restrict__ f1,
    const float* __restrict__ f2, const float* __restrict__ f3,
    __hip_bfloat16* __restrict__ tf) {
  __shared__ float tile[64][65];
  const int b = blockIdx.x;  // 5440 total
  const float* src;
  int S, lg;
  size_t dstoff;
  int sb;
  if (b < 4096) {        // level0: 1024 sp-tiles x 4 cgroups
    src = f0; S = 65536; lg = 10; dstoff = 0;     sb = b;
  } else if (b < 5120) { // level1: 256 x 4
    src = f1; S = 16384; lg = 8;  dstoff = 65536; sb = b - 4096;
  } else if (b < 5376) { // level2: 64 x 4
    src = f2; S = 4096;  lg = 6;  dstoff = 81920; sb = b - 5120;
  } else {               // level3: 16 x 4
    src = f3; S = 1024;  lg = 4;  dstoff = 86016; sb = b - 5376;
  }
  const int nsp_m1 = (1 << lg) - 1;
  const int s0 = (sb & nsp_m1) * 64;
  const int c0 = (sb >> lg) * 64;

  const int t = threadIdx.x;
  {  // load: float4 along spatial, 256B coalesced runs per channel row
    const int cl = t >> 4;          // 0..15
    const int sp4 = (t & 15) * 4;   // 0..60
    #pragma unroll
    for (int j = 0; j < 4; ++j) {
      const int c = cl + 16 * j;
      const float4 v = *(const float4*)(src + (size_t)(c0 + c) * S + s0 + sp4);
      tile[c][sp4 + 0] = v.x;
      tile[c][sp4 + 1] = v.y;
      tile[c][sp4 + 2] = v.z;
      tile[c][sp4 + 3] = v.w;
    }
  }
  __syncthreads();
  {  // store: gather 4 channels, convert, ushort4 stores, 128B runs
    const int spl = t >> 4;         // 0..15
    const int c4 = (t & 15) * 4;    // 0..60
    __hip_bfloat16* dst = tf + (dstoff + (size_t)s0) * C_CH + c0;
    #pragma unroll
    for (int j = 0; j < 4; ++j) {
      const int sp = spl + 16 * j;
      union { ushort4 u; __hip_bfloat16 h[4]; } p;
      p.h[0] = __float2bfloat16(tile[c4 + 0][sp]);
      p.h[1] = __float2bfloat16(tile[c4 + 1][sp]);
      p.h[2] = __float2bfloat16(tile[c4 + 2][sp]);
      p.h[3] = __float2bfloat16(tile[c4 + 3][sp]);
      *(ushort4*)(dst + (size_t)sp * C_CH + c4) = p.u;
    }
  }
}

__device__ __forceinline__ float bfu(unsigned short s) {
  union { unsigned u; float f; } v;
  v.u = (unsigned)s << 16;
  return v.f;
}

// ---------------------------------------------------------------------------
// ROI Align + 2x2 max pool, transposed bf16 path.
// One 64-lane wave per (proposal, oh, gx-half). half 0: gx 0-7 -> ow 0-3,
// half 1: gx 8-13 -> ow 4-6 (pool pairs never straddle the split).
// Lane covers channels 4L..4L+3 via ushort4 loads (512 B/wave/load).
// Grid 512 x 7 x 2 = 7168 waves (~28/CU); gx-half fully unrolled for MLP.
// ---------------------------------------------------------------------------
__global__ __launch_bounds__(64) void roi_bf16(
    const unsigned short* __restrict__ tf,
    const float* __restrict__ proposals, float* __restrict__ out) {
  __shared__ int xo0[14], xo1[14];
  __shared__ float wxa[14], wxb[14];
  __shared__ int yo_s[4];   // {y0,y1}(gy0), {y0,y1}(gy1)  (pre-scaled offsets)
  __shared__ float wy_s[4]; // {wya,wyb}(gy0), {wya,wyb}(gy1)

  const int n = blockIdx.x;
  const int oh = blockIdx.y;
  const int half = blockIdx.z;
  const int lane = threadIdx.x;

  const float px1 = proposals[n * 4 + 0];
  const float py1 = proposals[n * 4 + 1];
  const float px2 = proposals[n * 4 + 2];
  const float py2 = proposals[n * 4 + 3];
  float lt = 2.0f + log2f(sqrtf((px2 - px1) * (py2 - py1)) / 224.0f);
  int lvl = (int)floorf(lt);
  lvl = lvl < 0 ? 0 : (lvl > 3 ? 3 : lvl);

  const float scales[4] = {0.25f, 0.125f, 0.0625f, 0.03125f};
  const int sizes[4] = {256, 128, 64, 32};
  const int offs[4] = {0, 65536, 81920, 86016};
  const float sc = scales[lvl];
  const int sz = sizes[lvl];

  const float bx1 = px1 * sc, by1 = py1 * sc;
  const float w_unit = ((px2 - px1) * sc / 7.0f) * 0.5f;
  const float h_unit = ((py2 - py1) * sc / 7.0f) * 0.5f;

  if (lane < 14) {
    const int i = lane;
    float x = bx1 + ((float)i + 0.5f) * w_unit;
    int xf = (int)floorf(x);
    int x0 = min(max(xf, 0), sz - 1);
    int x1 = min(max(xf + 1, 0), sz - 1);
    wxa[i] = (float)x1 - x;  // matches ref incl. clipped extrapolation
    wxb[i] = x - (float)x0;
    xo0[i] = x0 * C_CH;
    xo1[i] = x1 * C_CH;
  } else if (lane >= 32 && lane < 34) {
    const int j = lane - 32;  // gy = 2*oh + j
    float y = by1 + ((float)(2 * oh + j) + 0.5f) * h_unit;
    int yf = (int)floorf(y);
    int y0 = min(max(yf, 0), sz - 1);
    int y1 = min(max(yf + 1, 0), sz - 1);
    yo_s[j * 2 + 0] = y0 * sz * C_CH;
    yo_s[j * 2 + 1] = y1 * sz * C_CH;
    wy_s[j * 2 + 0] = (float)y1 - y;
    wy_s[j * 2 + 1] = y - (float)y0;
  }
  __syncthreads();

  const unsigned short* base = tf + (size_t)offs[lvl] * C_CH + lane * 4;
  const unsigned short* r00 = base + yo_s[0];  // gy0, y0
  const unsigned short* r01 = base + yo_s[1];  // gy0, y1
  const unsigned short* r10 = base + yo_s[2];  // gy1, y0
  const unsigned short* r11 = base + yo_s[3];  // gy1, y1
  const float wy0a = wy_s[0], wy0b = wy_s[1];
  const float wy1a = wy_s[2], wy1b = wy_s[3];

  const int gx0 = half * 8;       // 0 or 8
  const int ngx = half ? 6 : 8;   // wave-uniform

  float mm[4][4];
  #pragma unroll
  for (int j = 0; j < 4; ++j)
    #pragma unroll
    for (int k = 0; k < 4; ++k) mm[j][k] = -INFINITY;

  #pragma unroll
  for (int g = 0; g < 8; ++g) {
    if (g >= ngx) break;  // wave-uniform
    const int gx = gx0 + g;
    const int xa = xo0[gx], xb = xo1[gx];
    const ushort4 A0 = *(const ushort4*)(r00 + xa);
    const ushort4 A1 = *(const ushort4*)(r00 + xb);
    const ushort4 B0 = *(const ushort4*)(r01 + xa);
    const ushort4 B1 = *(const ushort4*)(r01 + xb);
    const ushort4 C0 = *(const ushort4*)(r10 + xa);
    const ushort4 C1 = *(const ushort4*)(r10 + xb);
    const ushort4 D0 = *(const ushort4*)(r11 + xa);
    const ushort4 D1 = *(const ushort4*)(r11 + xb);
    const float fa = wxa[gx], fb = wxb[gx];
    const int j = g >> 1;
    const unsigned short* a0 = (const unsigned short*)&A0;
    const unsigned short* a1 = (const unsigned short*)&A1;
    const unsigned short* b0 = (const unsigned short*)&B0;
    const unsigned short* b1 = (const unsigned short*)&B1;
    const unsigned short* c0 = (const unsigned short*)&C0;
    const unsigned short* c1 = (const unsigned short*)&C1;
    const unsigned short* d0 = (const unsigned short*)&D0;
    const unsigned short* d1 = (const unsigned short*)&D1;
    #pragma unroll
    for (int k = 0; k < 4; ++k) {
      const float h00 = fa * bfu(a0[k]) + fb * bfu(a1[k]);
      const float h01 = fa * bfu(b0[k]) + fb * bfu(b1[k]);
      const float va = wy0a * h00 + wy0b * h01;
      const float h10 = fa * bfu(c0[k]) + fb * bfu(c1[k]);
      const float h11 = fa * bfu(d0[k]) + fb * bfu(d1[k]);
      const float vb = wy1a * h10 + wy1b * h11;
      mm[j][k] = fmaxf(mm[j][k], fmaxf(va, vb));
    }
  }

  // Stores: per lane 4 channels x (4|3) contiguous floats.
  const int now = half ? 3 : 4;
  float* ob = out + ((size_t)n * C_CH + lane * 4) * 49 + oh * 7 + half * 4;
  #pragma unroll
  for (int k = 0; k < 4; ++k)
    for (int j = 0; j < now; ++j) ob[k * 49 + j] = mm[j][k];
}

// ---------------------------------------------------------------------------
// Fallback (no workspace): direct (C,H,W) reads. Correctness-only path.
// ---------------------------------------------------------------------------
__global__ __launch_bounds__(64) void roi_fallback(
    const float* __restrict__ f0, const float* __restrict__ f1,
    const float* __restrict__ f2, const float* __restrict__ f3,
    const float* __restrict__ proposals, float* __restrict__ out) {
  __shared__ int xo0[14], xo1[14], yo0[14], yo1[14];
  __shared__ float wxa[14], wxb[14], wya[14], wyb[14];
  const int n = blockIdx.x;
  const int cblk = blockIdx.y;
  const int lane = threadIdx.x;
  const int c = cblk * 64 + lane;
  const float px1 = proposals[n * 4 + 0];
  const float py1 = proposals[n * 4 + 1];
  const float px2 = proposals[n * 4 + 2];
  const float py2 = proposals[n * 4 + 3];
  float lt = 2.0f + log2f(sqrtf((px2 - px1) * (py2 - py1)) / 224.0f);
  int lvl = (int)floorf(lt);
  lvl = lvl < 0 ? 0 : (lvl > 3 ? 3 : lvl);
  const float scales[4] = {0.25f, 0.125f, 0.0625f, 0.03125f};
  const int sizes[4] = {256, 128, 64, 32};
  const float sc = scales[lvl];
  const int sz = sizes[lvl];
  const float bx1 = px1 * sc, by1 = py1 * sc;
  const float w_unit = ((px2 - px1) * sc / 7.0f) * 0.5f;
  const float h_unit = ((py2 - py1) * sc / 7.0f) * 0.5f;
  if (lane < 14) {
    float x = bx1 + ((float)lane + 0.5f) * w_unit;
    int xf = (int)floorf(x);
    int x0 = min(max(xf, 0), sz - 1);
    int x1 = min(max(xf + 1, 0), sz - 1);
    wxa[lane] = (float)x1 - x;
    wxb[lane] = x - (float)x0;
    xo0[lane] = x0;
    xo1[lane] = x1;
  } else if (lane >= 32 && lane < 46) {
    const int i = lane - 32;
    float y = by1 + ((float)i + 0.5f) * h_unit;
    int yf = (int)floorf(y);
    int y0 = min(max(yf, 0), sz - 1);
    int y1 = min(max(yf + 1, 0), sz - 1);
    wya[i] = (float)y1 - y;
    wyb[i] = y - (float)y0;
    yo0[i] = y0 * sz;
    yo1[i] = y1 * sz;
  }
  __syncthreads();
  const float* fl = (lvl == 0) ? f0 : (lvl == 1) ? f1 : (lvl == 2) ? f2 : f3;
  const float* base = fl + (size_t)c * sz * sz;
  for (int oh = 0; oh < 7; ++oh) {
    float mm[7];
    #pragma unroll
    for (int ow = 0; ow < 7; ++ow) mm[ow] = -INFINITY;
    #pragma unroll
    for (int sy = 0; sy < 2; ++sy) {
      const int gy = oh * 2 + sy;
      const float* r0 = base + yo0[gy];
      const float* r1 = base + yo1[gy];
      const float wy0 = wya[gy], wy1 = wyb[gy];
      #pragma unroll
      for (int gx = 0; gx < 14; ++gx) {
        float v = wy0 * (wxa[gx] * r0[xo0[gx]] + wxb[gx] * r0[xo1[gx]]) +
                  wy1 * (wxa[gx] * r1[xo0[gx]] + wxb[gx] * r1[xo1[gx]]);
        mm[gx >> 1] = fmaxf(mm[gx >> 1], v);
      }
    }
    #pragma unroll
    for (int ow = 0; ow < 7; ++ow)
      out[((size_t)n * C_CH + c) * 49 + oh * 7 + ow] = mm[ow];
  }
}

extern "C" void kernel_launch(void* const* d_in, const int* in_sizes, int n_in,
                              void* d_out, int out_size, void* d_ws,
                              size_t ws_size, hipStream_t stream) {
  const float* f0 = (const float*)d_in[0];
  const float* f1 = (const float*)d_in[1];
  const float* f2 = (const float*)d_in[2];
  const float* f3 = (const float*)d_in[3];
  const float* props = (const float*)d_in[4];
  float* out = (float*)d_out;
  const int N = in_sizes[4] / 4;

  const size_t needed = (size_t)87040 * C_CH * sizeof(__hip_bfloat16);  // 44.6MB
  if (ws_size >= needed) {
    __hip_bfloat16* tf = (__hip_bfloat16*)d_ws;
    transpose_all<<<5440, 256, 0, stream>>>(f0, f1, f2, f3, tf);
    roi_bf16<<<dim3(N, 7, 2), 64, 0, stream>>>((const unsigned short*)tf,
                                               props, out);
  } else {
    roi_fallback<<<dim3(N, 4), 64, 0, stream>>>(f0, f1, f2, f3, props, out);
  }
}

// Round 5
// 144.863 us; speedup vs baseline: 1.1738x; 1.1738x over previous
//
#include <hip/hip_runtime.h>
#include <hip/hip_bf16.h>
#include <math.h>

#define C_CH 256

// ---------------------------------------------------------------------------
// Transpose all 4 FPN levels from fp32 (C,H,W) to bf16 (H*W, C) in d_ws.
// 64-spatial x 64-channel tiles, 256 threads, 16.6 KB LDS.
// At the 223 MB (178 rd + 45 wr) / 6.3 TB/s BW roofline (~35 us).
// ---------------------------------------------------------------------------
__global__ __launch_bounds__(256) void transpose_all(
    const float* __restrict__ f0, const float* __restrict__ f1,
    const float* __restrict__ f2, const float* __restrict__ f3,
    __hip_bfloat16* __restrict__ tf) {
  __shared__ float tile[64][65];
  const int b = blockIdx.x;  // 5440 total
  const float* src;
  int S, lg;
  size_t dstoff;
  int sb;
  if (b < 4096) {        // level0: 1024 sp-tiles x 4 cgroups
    src = f0; S = 65536; lg = 10; dstoff = 0;     sb = b;
  } else if (b < 5120) { // level1: 256 x 4
    src = f1; S = 16384; lg = 8;  dstoff = 65536; sb = b - 4096;
  } else if (b < 5376) { // level2: 64 x 4
    src = f2; S = 4096;  lg = 6;  dstoff = 81920; sb = b - 5120;
  } else {               // level3: 16 x 4
    src = f3; S = 1024;  lg = 4;  dstoff = 86016; sb = b - 5376;
  }
  const int nsp_m1 = (1 << lg) - 1;
  const int s0 = (sb & nsp_m1) * 64;
  const int c0 = (sb >> lg) * 64;

  const int t = threadIdx.x;
  {  // load: float4 along spatial, 256B coalesced runs per channel row
    const int cl = t >> 4;          // 0..15
    const int sp4 = (t & 15) * 4;   // 0..60
    #pragma unroll
    for (int j = 0; j < 4; ++j) {
      const int c = cl + 16 * j;
      const float4 v = *(const float4*)(src + (size_t)(c0 + c) * S + s0 + sp4);
      tile[c][sp4 + 0] = v.x;
      tile[c][sp4 + 1] = v.y;
      tile[c][sp4 + 2] = v.z;
      tile[c][sp4 + 3] = v.w;
    }
  }
  __syncthreads();
  {  // store: gather 4 channels, convert, ushort4 stores, 128B runs
    const int spl = t >> 4;         // 0..15
    const int c4 = (t & 15) * 4;    // 0..60
    __hip_bfloat16* dst = tf + (dstoff + (size_t)s0) * C_CH + c0;
    #pragma unroll
    for (int j = 0; j < 4; ++j) {
      const int sp = spl + 16 * j;
      union { ushort4 u; __hip_bfloat16 h[4]; } p;
      p.h[0] = __float2bfloat16(tile[c4 + 0][sp]);
      p.h[1] = __float2bfloat16(tile[c4 + 1][sp]);
      p.h[2] = __float2bfloat16(tile[c4 + 2][sp]);
      p.h[3] = __float2bfloat16(tile[c4 + 3][sp]);
      *(ushort4*)(dst + (size_t)sp * C_CH + c4) = p.u;
    }
  }
}

__device__ __forceinline__ float bfu(unsigned short s) {
  union { unsigned u; float f; } v;
  v.u = (unsigned)s << 16;
  return v.f;
}

#define OPAD 260  // obuf row stride (floats); %4==0 keeps float4 writes aligned

// ---------------------------------------------------------------------------
// ROI Align + 2x2 max pool, transposed bf16 path.
// One 512-thread block (8 waves) per proposal. Waves 0-6 each compute one
// output row oh (all 14 gx, fully unrolled -> deep MLP; lane covers channels
// 4L..4L+3 via ushort4 loads, 512 B/wave/load). Results staged in LDS as
// obuf[p][OPAD] (compute side: 7 conflict-free float4 row writes per lane),
// then one fully-coalesced contiguous 50 KB block store to out — this is the
// fix for R4's 4x partial-line write amplification (WRITE 97 -> 26 MB).
// ---------------------------------------------------------------------------
__global__ __launch_bounds__(512) void roi_bf16(
    const unsigned short* __restrict__ tf,
    const float* __restrict__ proposals, float* __restrict__ out) {
  __shared__ int xo0[14], xo1[14], yo0[14], yo1[14];
  __shared__ float wxa[14], wxb[14], wya[14], wyb[14];
  __shared__ float obuf[49 * OPAD];

  const int n = blockIdx.x;
  const int t = threadIdx.x;
  const int lane = t & 63;
  const int w = t >> 6;  // wave id 0..7

  const float px1 = proposals[n * 4 + 0];
  const float py1 = proposals[n * 4 + 1];
  const float px2 = proposals[n * 4 + 2];
  const float py2 = proposals[n * 4 + 3];
  float lt = 2.0f + log2f(sqrtf((px2 - px1) * (py2 - py1)) / 224.0f);
  int lvl = (int)floorf(lt);
  lvl = lvl < 0 ? 0 : (lvl > 3 ? 3 : lvl);

  const float scales[4] = {0.25f, 0.125f, 0.0625f, 0.03125f};
  const int sizes[4] = {256, 128, 64, 32};
  const int offs[4] = {0, 65536, 81920, 86016};
  const float sc = scales[lvl];
  const int sz = sizes[lvl];

  const float bx1 = px1 * sc, by1 = py1 * sc;
  const float w_unit = ((px2 - px1) * sc / 7.0f) * 0.5f;
  const float h_unit = ((py2 - py1) * sc / 7.0f) * 0.5f;

  if (t < 14) {
    const int i = t;
    float x = bx1 + ((float)i + 0.5f) * w_unit;
    int xf = (int)floorf(x);
    int x0 = min(max(xf, 0), sz - 1);
    int x1 = min(max(xf + 1, 0), sz - 1);
    wxa[i] = (float)x1 - x;  // matches ref incl. clipped extrapolation
    wxb[i] = x - (float)x0;
    xo0[i] = x0 * C_CH;
    xo1[i] = x1 * C_CH;
  } else if (t >= 64 && t < 78) {
    const int i = t - 64;
    float y = by1 + ((float)i + 0.5f) * h_unit;
    int yf = (int)floorf(y);
    int y0 = min(max(yf, 0), sz - 1);
    int y1 = min(max(yf + 1, 0), sz - 1);
    wya[i] = (float)y1 - y;
    wyb[i] = y - (float)y0;
    yo0[i] = y0 * sz * C_CH;
    yo1[i] = y1 * sz * C_CH;
  }
  __syncthreads();

  if (w < 7) {  // wave-uniform: waves 0-6 compute, wave 7 only helps store
    const int oh = w;
    const int gy0 = 2 * oh, gy1 = 2 * oh + 1;
    const unsigned short* base = tf + (size_t)offs[lvl] * C_CH + lane * 4;
    const unsigned short* r00 = base + yo0[gy0];
    const unsigned short* r01 = base + yo1[gy0];
    const unsigned short* r10 = base + yo0[gy1];
    const unsigned short* r11 = base + yo1[gy1];
    const float wy0a = wya[gy0], wy0b = wyb[gy0];
    const float wy1a = wya[gy1], wy1b = wyb[gy1];

    float mm[7][4];
    #pragma unroll
    for (int j = 0; j < 7; ++j)
      #pragma unroll
      for (int k = 0; k < 4; ++k) mm[j][k] = -INFINITY;

    #pragma unroll
    for (int gx = 0; gx < 14; ++gx) {
      const int xa = xo0[gx], xb = xo1[gx];
      const ushort4 A0 = *(const ushort4*)(r00 + xa);
      const ushort4 A1 = *(const ushort4*)(r00 + xb);
      const ushort4 B0 = *(const ushort4*)(r01 + xa);
      const ushort4 B1 = *(const ushort4*)(r01 + xb);
      const ushort4 C0 = *(const ushort4*)(r10 + xa);
      const ushort4 C1 = *(const ushort4*)(r10 + xb);
      const ushort4 D0 = *(const ushort4*)(r11 + xa);
      const ushort4 D1 = *(const ushort4*)(r11 + xb);
      const float fa = wxa[gx], fb = wxb[gx];
      const int j = gx >> 1;
      const unsigned short* a0 = (const unsigned short*)&A0;
      const unsigned short* a1 = (const unsigned short*)&A1;
      const unsigned short* b0 = (const unsigned short*)&B0;
      const unsigned short* b1 = (const unsigned short*)&B1;
      const unsigned short* c0 = (const unsigned short*)&C0;
      const unsigned short* c1 = (const unsigned short*)&C1;
      const unsigned short* d0 = (const unsigned short*)&D0;
      const unsigned short* d1 = (const unsigned short*)&D1;
      #pragma unroll
      for (int k = 0; k < 4; ++k) {
        const float h00 = fa * bfu(a0[k]) + fb * bfu(a1[k]);
        const float h01 = fa * bfu(b0[k]) + fb * bfu(b1[k]);
        const float va = wy0a * h00 + wy0b * h01;
        const float h10 = fa * bfu(c0[k]) + fb * bfu(c1[k]);
        const float h11 = fa * bfu(d0[k]) + fb * bfu(d1[k]);
        const float vb = wy1a * h10 + wy1b * h11;
        mm[j][k] = fmaxf(mm[j][k], fmaxf(va, vb));
      }
    }

    // Stage: obuf[p][c], p = oh*7+ow. float4 over the 4 channels: the wave
    // writes one contiguous 1 KB row per ow -> conflict-free ds_write_b128.
    #pragma unroll
    for (int ow = 0; ow < 7; ++ow) {
      float4 v = make_float4(mm[ow][0], mm[ow][1], mm[ow][2], mm[ow][3]);
      *(float4*)&obuf[(oh * 7 + ow) * OPAD + lane * 4] = v;
    }
  }
  __syncthreads();

  // Contiguous coalesced block store: out[n*12544 + i], i = c*49 + p.
  float* ob = out + (size_t)n * (C_CH * 49);
  for (int i = t; i < C_CH * 49; i += 512) {
    const unsigned c = (unsigned)i / 49u;
    const unsigned p = (unsigned)i - c * 49u;
    ob[i] = obuf[p * OPAD + c];
  }
}

// ---------------------------------------------------------------------------
// Fallback (no workspace): direct (C,H,W) reads. Correctness-only path.
// ---------------------------------------------------------------------------
__global__ __launch_bounds__(64) void roi_fallback(
    const float* __restrict__ f0, const float* __restrict__ f1,
    const float* __restrict__ f2, const float* __restrict__ f3,
    const float* __restrict__ proposals, float* __restrict__ out) {
  __shared__ int xo0[14], xo1[14], yo0[14], yo1[14];
  __shared__ float wxa[14], wxb[14], wya[14], wyb[14];
  const int n = blockIdx.x;
  const int cblk = blockIdx.y;
  const int lane = threadIdx.x;
  const int c = cblk * 64 + lane;
  const float px1 = proposals[n * 4 + 0];
  const float py1 = proposals[n * 4 + 1];
  const float px2 = proposals[n * 4 + 2];
  const float py2 = proposals[n * 4 + 3];
  float lt = 2.0f + log2f(sqrtf((px2 - px1) * (py2 - py1)) / 224.0f);
  int lvl = (int)floorf(lt);
  lvl = lvl < 0 ? 0 : (lvl > 3 ? 3 : lvl);
  const float scales[4] = {0.25f, 0.125f, 0.0625f, 0.03125f};
  const int sizes[4] = {256, 128, 64, 32};
  const float sc = scales[lvl];
  const int sz = sizes[lvl];
  const float bx1 = px1 * sc, by1 = py1 * sc;
  const float w_unit = ((px2 - px1) * sc / 7.0f) * 0.5f;
  const float h_unit = ((py2 - py1) * sc / 7.0f) * 0.5f;
  if (lane < 14) {
    float x = bx1 + ((float)lane + 0.5f) * w_unit;
    int xf = (int)floorf(x);
    int x0 = min(max(xf, 0), sz - 1);
    int x1 = min(max(xf + 1, 0), sz - 1);
    wxa[lane] = (float)x1 - x;
    wxb[lane] = x - (float)x0;
    xo0[lane] = x0;
    xo1[lane] = x1;
  } else if (lane >= 32 && lane < 46) {
    const int i = lane - 32;
    float y = by1 + ((float)i + 0.5f) * h_unit;
    int yf = (int)floorf(y);
    int y0 = min(max(yf, 0), sz - 1);
    int y1 = min(max(yf + 1, 0), sz - 1);
    wya[i] = (float)y1 - y;
    wyb[i] = y - (float)y0;
    yo0[i] = y0 * sz;
    yo1[i] = y1 * sz;
  }
  __syncthreads();
  const float* fl = (lvl == 0) ? f0 : (lvl == 1) ? f1 : (lvl == 2) ? f2 : f3;
  const float* base = fl + (size_t)c * sz * sz;
  for (int oh = 0; oh < 7; ++oh) {
    float mm[7];
    #pragma unroll
    for (int ow = 0; ow < 7; ++ow) mm[ow] = -INFINITY;
    #pragma unroll
    for (int sy = 0; sy < 2; ++sy) {
      const int gy = oh * 2 + sy;
      const float* r0 = base + yo0[gy];
      const float* r1 = base + yo1[gy];
      const float wy0 = wya[gy], wy1 = wyb[gy];
      #pragma unroll
      for (int gx = 0; gx < 14; ++gx) {
        float v = wy0 * (wxa[gx] * r0[xo0[gx]] + wxb[gx] * r0[xo1[gx]]) +
                  wy1 * (wxa[gx] * r1[xo0[gx]] + wxb[gx] * r1[xo1[gx]]);
        mm[gx >> 1] = fmaxf(mm[gx >> 1], v);
      }
    }
    #pragma unroll
    for (int ow = 0; ow < 7; ++ow)
      out[((size_t)n * C_CH + c) * 49 + oh * 7 + ow] = mm[ow];
  }
}

extern "C" void kernel_launch(void* const* d_in, const int* in_sizes, int n_in,
                              void* d_out, int out_size, void* d_ws,
                              size_t ws_size, hipStream_t stream) {
  const float* f0 = (const float*)d_in[0];
  const float* f1 = (const float*)d_in[1];
  const float* f2 = (const float*)d_in[2];
  const float* f3 = (const float*)d_in[3];
  const float* props = (const float*)d_in[4];
  float* out = (float*)d_out;
  const int N = in_sizes[4] / 4;

  const size_t needed = (size_t)87040 * C_CH * sizeof(__hip_bfloat16);  // 44.6MB
  if (ws_size >= needed) {
    __hip_bfloat16* tf = (__hip_bfloat16*)d_ws;
    transpose_all<<<5440, 256, 0, stream>>>(f0, f1, f2, f3, tf);
    roi_bf16<<<N, 512, 0, stream>>>((const unsigned short*)tf, props, out);
  } else {
    roi_fallback<<<dim3(N, 4), 64, 0, stream>>>(f0, f1, f2, f3, props, out);
  }
}